// Round 4
// baseline (1812.288 us; speedup 1.0000x reference)
//
#include <hip/hip_runtime.h>

// LSTM_38869454028951: B=512, T=365, F=16, H=256, 2 layers + linear head.
// Round 8: Round-7 (direct-from-L2 MFMA fragments) hardened for register
// pressure: fragment pipeline depth 4 -> 2 (F0/F1 reused), peak live frag
// regs 64 -> 32 VGPR. h published in fragment-tiled plane-split layout
// [slot][bg][kblk][quad][plane][row][16B]; GEMM waves load A-fragments
// straight from L2 (agent u64 loads, coalesced). No restage, no A-LDS,
// 2 barriers/body. Flag protocol: per-updater-wave sub-flags (R6).

#define T_STEPS 365
#define XSTR 36   // x LDS row stride (u32)

typedef __attribute__((ext_vector_type(8))) short short8;
typedef __attribute__((ext_vector_type(4))) float float4_;
typedef __attribute__((ext_vector_type(4))) unsigned int uint4_;
typedef unsigned long long u64;
typedef unsigned int u32;

#define MFMA16(a, b, c) __builtin_amdgcn_mfma_f32_16x16x32_bf16((a), (b), (c), 0, 0, 0)
#define LD64(p) __hip_atomic_load((p), __ATOMIC_RELAXED, __HIP_MEMORY_SCOPE_AGENT)

__device__ __forceinline__ unsigned short f2bf(float v) {
    union { float f; u32 u; } a; a.f = v;
    u32 r = a.u + 0x7fffu + ((a.u >> 16) & 1u);  // RNE
    return (unsigned short)(r >> 16);
}
__device__ __forceinline__ float bf2f(unsigned short h) {
    union { u32 u; float f; } a; a.u = ((u32)h) << 16; return a.f;
}
__device__ __forceinline__ u32 packhl(float v) {
    unsigned short hi = f2bf(v);
    unsigned short lo = f2bf(v - bf2f(hi));
    return ((u32)hi << 16) | (u32)lo;
}
__device__ __forceinline__ float sigm(float x)  { return 1.f / (1.f + __expf(-x)); }
__device__ __forceinline__ float tanh_(float x) { return 2.f / (1.f + __expf(-2.f * x)) - 1.f; }

// unpack 8 packed u32 (hi16|lo16) -> hi short8 + lo short8 (k-order preserved)
__device__ __forceinline__ void unpk(uint4_ a, uint4_ b, short8& hi, short8& lo) {
    union U { u32 d[4]; short8 s; } H, L;
    H.d[0] = __builtin_amdgcn_perm(a.y, a.x, 0x07060302u);
    H.d[1] = __builtin_amdgcn_perm(a.w, a.z, 0x07060302u);
    H.d[2] = __builtin_amdgcn_perm(b.y, b.x, 0x07060302u);
    H.d[3] = __builtin_amdgcn_perm(b.w, b.z, 0x07060302u);
    L.d[0] = __builtin_amdgcn_perm(a.y, a.x, 0x05040100u);
    L.d[1] = __builtin_amdgcn_perm(a.w, a.z, 0x05040100u);
    L.d[2] = __builtin_amdgcn_perm(b.y, b.x, 0x05040100u);
    L.d[3] = __builtin_amdgcn_perm(b.w, b.z, 0x05040100u);
    hi = H.s; lo = L.s;
}

// ---------------- prep: blocked hi/lo weights + biases (UNCHANGED layout) ----------------
// w1blk: [64 tiles][9 ks][16 cols][32 k]; ks<8: Whh1; ks==8: Wih1 (K pad 16->32)
// w2blk: [64][16][16][32]; ks<8: Wih2 (h1 input), ks>=8: Whh2 (h2 input)
__global__ void prep_w(
    const float* __restrict__ Wih1, const float* __restrict__ Whh1,
    const float* __restrict__ bih1, const float* __restrict__ bhh1,
    const float* __restrict__ Wih2, const float* __restrict__ Whh2,
    const float* __restrict__ bih2, const float* __restrict__ bhh2,
    unsigned short* __restrict__ w1h, unsigned short* __restrict__ w1l,
    unsigned short* __restrict__ w2h, unsigned short* __restrict__ w2l,
    float* __restrict__ bias1, float* __restrict__ bias2)
{
    const int tile = blockIdx.x;          // 64
    const int g = tile >> 4, ns = tile & 15;
    const int tid = threadIdx.x;          // 256

    for (int idx = tid; idx < 9 * 512; idx += 256) {
        int ks = idx >> 9, off = idx & 511, r = off >> 5, kk = off & 31;
        int R = g * 256 + ns * 16 + r;
        float v;
        if (ks < 8)       v = Whh1[R * 256 + ks * 32 + kk];
        else if (kk < 16) v = Wih1[R * 16 + kk];
        else              v = 0.f;
        unsigned short h = f2bf(v);
        size_t d = (size_t)(tile * 9 + ks) * 512 + off;
        w1h[d] = h; w1l[d] = f2bf(v - bf2f(h));
    }
    for (int idx = tid; idx < 16 * 512; idx += 256) {
        int ks = idx >> 9, off = idx & 511, r = off >> 5, kk = off & 31;
        int R = g * 256 + ns * 16 + r;
        int k = ks * 32 + kk;
        float v = (k < 256) ? Wih2[R * 256 + k] : Whh2[R * 256 + (k - 256)];
        unsigned short h = f2bf(v);
        size_t d = (size_t)(tile * 16 + ks) * 512 + off;
        w2h[d] = h; w2l[d] = f2bf(v - bf2f(h));
    }
    if (tid < 16) {
        int R = g * 256 + ns * 16 + tid;
        bias1[R] = bih1[R] + bhh1[R];
        bias2[R] = bih2[R] + bhh2[R];
    }
}

// hb tiled layout, u32 index within a (slot,bg) chunk of 8192:
//   kblk*1024 + quad*256 + plane*128 + row*4 + i4     (k = quad*8 + plane*4 + i4)
// Fragment load (lane): u64 base = chunk/2 + kblk*512 + quad*128 + r16*2;
//   offs {0,1,64,65} = rows 0-15 {p0w0,p0w1,p1w0,p1w1}; +32 for rows 16-31.

// ---------------- main ----------------
__global__ __launch_bounds__(512, 2) void lstm_main(
    const float* __restrict__ x,
    const unsigned short* __restrict__ w1h, const unsigned short* __restrict__ w1l,
    const unsigned short* __restrict__ w2h, const unsigned short* __restrict__ w2l,
    const float* __restrict__ bias1, const float* __restrict__ bias2,
    u32* hb1, u32* hb2, u32* prog,
    const float* __restrict__ Wlin, const float* __restrict__ blin,
    float* __restrict__ out)
{
    __shared__ __align__(16) u32 xbuf[32 * XSTR];         // 4.6 KB (cols 16..31 zero)
    __shared__ __align__(16) float zb1[3 * 64 * 36];      // 27 KB  L1 partials
    __shared__ __align__(16) float zb2[5 * 64 * 36];      // 45 KB  L2 partials
    __shared__ __align__(16) float hp[32][17];

    const int tid  = threadIdx.x;
    const int lane = tid & 63;
    const int wv   = tid >> 6;            // 8 waves
    const int quad = lane >> 4;
    const int r16  = lane & 15;
    const int bg   = blockIdx.x & 15;     // batch group (all peers same XCD)
    const int ns   = blockIdx.x >> 4;     // col slice

    u32* myprog = prog + bg * 64;         // [ns 0..15][updater wave 0..3]

    // ---- per-wave K-slot table (sid = weight ks index; -1 unused) ----
    // L1 (waves 0-2): sid 0..7 = h1 (Whh1), sid 8 = x (Wih1)
    // L2 (waves 3-7): sid 0..7 = h1 (Wih2), sid 8..15 = h2 (Whh2)
    const bool isL1 = (wv < 3);
    int s0, s1, s2, s3;
    if      (wv == 0) { s0 = 0;  s1 = 1;  s2 = 2;  s3 = -1; }
    else if (wv == 1) { s0 = 3;  s1 = 4;  s2 = 5;  s3 = -1; }
    else if (wv == 2) { s0 = 6;  s1 = 7;  s2 = 8;  s3 = -1; }
    else if (wv == 3) { s0 = 0;  s1 = 1;  s2 = 2;  s3 = 3;  }
    else if (wv == 4) { s0 = 4;  s1 = 5;  s2 = 6;  s3 = -1; }
    else if (wv == 5) { s0 = 7;  s1 = 8;  s2 = 9;  s3 = -1; }
    else if (wv == 6) { s0 = 10; s1 = 11; s2 = 12; s3 = -1; }
    else              { s0 = 13; s1 = 14; s2 = 15; s3 = -1; }

    // ---- preload weights (all 4 gates for this wave's K-slots) ----
    const int loff = r16 * 32 + quad * 8;
    const unsigned short* WHsrc = isL1 ? w1h : w2h;
    const unsigned short* WLsrc = isL1 ? w1l : w2l;
    const int NK = isL1 ? 9 : 16;
    short8 WH[4][4], WL[4][4];
#pragma unroll
    for (int s = 0; s < 4; s++) {
        const int b = (s == 0) ? s0 : (s == 1) ? s1 : (s == 2) ? s2 : s3;
#pragma unroll
        for (int g = 0; g < 4; g++) {
            if (b >= 0) {
                size_t off = ((size_t)((g * 16 + ns) * NK + b)) * 512 + loff;
                WH[g][s] = *(const short8*)(WHsrc + off);
                WL[g][s] = *(const short8*)(WLsrc + off);
            } else {
                WH[g][s] = short8{0,0,0,0,0,0,0,0};
                WL[g][s] = short8{0,0,0,0,0,0,0,0};
            }
        }
    }

    // ---- updater state (threads 0..255: 0-127 L1, 128-255 L2; 4 cells each) ----
    float bi[4] = {0.f, 0.f, 0.f, 0.f};
    if (tid < 256) {
        const float* bsrc = (tid < 128) ? bias1 : bias2;
        int colg = ns * 16 + (tid & 15);
#pragma unroll
        for (int g = 0; g < 4; g++) bi[g] = bsrc[g * 256 + colg];
    }
    float cst[4] = {0.f, 0.f, 0.f, 0.f};

    // ---- zero xbuf (incl. pad cols); stage x_0 ----
    for (int i = tid; i < 32 * XSTR; i += 512) xbuf[i] = 0u;
    __syncthreads();
    {
        int row = tid >> 4, col = tid & 15;
        float v = x[((size_t)(bg * 32 + row) * T_STEPS + 0) * 16 + col];
        xbuf[row * XSTR + col] = packhl(v);
    }
    __syncthreads();

#define ISSUE(Fv, sid) do {                                                   \
        if ((sid) >= 0 && !(isL1 && (sid) == 8)) {                            \
            const u64* bp_ = (isL1 || (sid) < 8) ? h1base : h2base;           \
            int kb_ = (isL1 || (sid) < 8) ? (sid) : ((sid) - 8);              \
            const u64* a_ = bp_ + (size_t)kb_ * 512 + (size_t)quad * 128      \
                                + (size_t)r16 * 2;                            \
            Fv[0] = LD64(a_ + 0);  Fv[1] = LD64(a_ + 1);                      \
            Fv[2] = LD64(a_ + 64); Fv[3] = LD64(a_ + 65);                     \
            Fv[4] = LD64(a_ + 32); Fv[5] = LD64(a_ + 33);                     \
            Fv[6] = LD64(a_ + 96); Fv[7] = LD64(a_ + 97);                     \
        } } while (0)

#define PROC(Fv, sid, sreg) do {                                              \
        if ((sid) >= 0) {                                                     \
            uint4_ q00, q01, q10, q11;                                        \
            if (isL1 && (sid) == 8) {                                         \
                q00 = *(const uint4_*)&xbuf[r16 * XSTR + quad * 8];           \
                q01 = *(const uint4_*)&xbuf[r16 * XSTR + quad * 8 + 4];       \
                q10 = *(const uint4_*)&xbuf[(16 + r16) * XSTR + quad * 8];    \
                q11 = *(const uint4_*)&xbuf[(16 + r16) * XSTR + quad * 8 + 4];\
            } else {                                                          \
                union { u64 q[2]; uint4_ v; } u0_, u1_, u2_, u3_;             \
                u0_.q[0] = Fv[0]; u0_.q[1] = Fv[1]; q00 = u0_.v;              \
                u1_.q[0] = Fv[2]; u1_.q[1] = Fv[3]; q01 = u1_.v;              \
                u2_.q[0] = Fv[4]; u2_.q[1] = Fv[5]; q10 = u2_.v;              \
                u3_.q[0] = Fv[6]; u3_.q[1] = Fv[7]; q11 = u3_.v;              \
            }                                                                 \
            short8 ah0, al0, ah1, al1;                                        \
            unpk(q00, q01, ah0, al0);                                         \
            unpk(q10, q11, ah1, al1);                                         \
            _Pragma("unroll")                                                 \
            for (int g = 0; g < 4; g++) {                                     \
                acc[g][0] = MFMA16(ah0, WH[g][sreg], acc[g][0]);              \
                acc[g][0] = MFMA16(al0, WH[g][sreg], acc[g][0]);              \
                acc[g][0] = MFMA16(ah0, WL[g][sreg], acc[g][0]);              \
                acc[g][1] = MFMA16(ah1, WH[g][sreg], acc[g][1]);              \
                acc[g][1] = MFMA16(al1, WH[g][sreg], acc[g][1]);              \
                acc[g][1] = MFMA16(ah1, WL[g][sreg], acc[g][1]);              \
            }                                                                 \
        } } while (0)

    for (int t = 0; t <= T_STEPS; t++) {   // 366 bodies
        const int p = t & 1;

        // ---- poll: data for this body (flags >= t). t=0 passes trivially ----
        {
            const u32 tgt = (u32)t;
            while (__hip_atomic_load(&myprog[lane], __ATOMIC_RELAXED,
                                     __HIP_MEMORY_SCOPE_AGENT) < tgt)
                __builtin_amdgcn_s_sleep(1);
        }
        __syncthreads();   // B2: x(t) LDS writes visible; zb(t-1) reads done

        // ================= GEMM: fragments direct from L2 (depth-2) =========
        // GEMM(t) consumes h1_{t-1} (hb1 slot 1-p) and h2_{t-2} (hb2 slot p)
        const u64* h1base = (const u64*)hb1 + (size_t)((1 - p) * 16 + bg) * 4096;
        const u64* h2base = (const u64*)hb2 + (size_t)(p * 16 + bg) * 4096;

        float4_ acc[4][2];
        const float4_ z4 = {0.f, 0.f, 0.f, 0.f};
#pragma unroll
        for (int g = 0; g < 4; g++) { acc[g][0] = z4; acc[g][1] = z4; }

        u64 F0[8], F1[8];
        ISSUE(F0, s0); ISSUE(F1, s1);
        PROC(F0, s0, 0); ISSUE(F0, s2);
        PROC(F1, s1, 1); ISSUE(F1, s3);
        PROC(F0, s2, 2);
        PROC(F1, s3, 3);

        {   // zb partial store: [part][col 0..63][row 0..31 pad36]
            float* zbase = isL1 ? (zb1 + wv * (64 * 36)) : (zb2 + (wv - 3) * (64 * 36));
#pragma unroll
            for (int g = 0; g < 4; g++)
#pragma unroll
                for (int rt = 0; rt < 2; rt++)
                    *(float4_*)&zbase[(size_t)(g * 16 + r16) * 36 + rt * 16 + quad * 4] = acc[g][rt];
        }
        __syncthreads();   // B1: zb ready

        if (tid < 256) {
            // ---- update: thread owns (hcol, rowquad rq) -> 4 cells of one layer ----
            const bool is1 = (tid < 128);
            const int hcol = tid & 15;
            const int rq   = (tid >> 4) & 7;
            const float* zb = is1 ? zb1 : zb2;
            const int np = is1 ? 3 : 5;
            float4_ z[4];
#pragma unroll
            for (int g = 0; g < 4; g++) {
                float4_ s = {bi[g], bi[g], bi[g], bi[g]};
#pragma unroll
                for (int pw = 0; pw < 5; pw++) {
                    if (pw < np)
                        s += *(const float4_*)&zb[(size_t)(pw * 64 + g * 16 + hcol) * 36 + rq * 4];
                }
                z[g] = s;
            }
            u32* hb = is1 ? hb1 : hb2;
            const int slot = is1 ? p : (1 - p);
            const int gc = ns * 16 + hcol;
            const size_t ob = (size_t)(slot * 16 + bg) * 8192
                            + (gc >> 5) * 1024 + ((gc >> 3) & 3) * 256
                            + ((gc >> 2) & 1) * 128 + rq * 16 + (gc & 3);
#pragma unroll
            for (int j = 0; j < 4; j++) {
                float zi = z[0][j], zf = z[1][j], zg = z[2][j], zo = z[3][j];
                float nc = sigm(zf) * cst[j] + sigm(zi) * tanh_(zg);
                float h  = sigm(zo) * tanh_(nc);
                if (!is1 && t == 0) { nc = 0.f; h = 0.f; }   // h2_{-1} must stay 0
                cst[j] = nc;
                __hip_atomic_store(&hb[ob + (size_t)j * 4], packhl(h),
                                   __ATOMIC_RELAXED, __HIP_MEMORY_SCOPE_WORKGROUP);
            }
            // ---- per-wave drain + sub-flag ----
            asm volatile("s_waitcnt vmcnt(0)" ::: "memory");
            if (lane == 0)
                __hip_atomic_store(&myprog[ns * 4 + wv], (u32)(t + 1),
                                   __ATOMIC_RELAXED, __HIP_MEMORY_SCOPE_WORKGROUP);
        } else {
            // ---- stage x_{t+1} (2 values/thread), overlapped with update ----
            const int i0 = tid - 256;
            const int tn = (t + 1 <= T_STEPS - 1) ? (t + 1) : (T_STEPS - 1);
#pragma unroll
            for (int k = 0; k < 2; k++) {
                int idx = i0 + 256 * k;
                int row = idx >> 4, col = idx & 15;
                float v = x[((size_t)(bg * 32 + row) * T_STEPS + tn) * 16 + col];
                xbuf[row * XSTR + col] = packhl(v);
            }
        }
        // loop: next body's poll + B2 provide all ordering
    }

    // ---- head (ns==0): out[b] = h2_364 . Wlin + blin ; hb2 slot 0 ----
    if (ns != 0) return;
    {   // final poll: peers' last-body h2 publishes must be visible
        const u32 tgt = (u32)(T_STEPS + 1);
        while (__hip_atomic_load(&myprog[lane], __ATOMIC_RELAXED,
                                 __HIP_MEMORY_SCOPE_AGENT) < tgt)
            __builtin_amdgcn_s_sleep(1);
    }
    {
        int row = tid >> 4, seg = tid & 15;
        const size_t sb = (size_t)(0 * 16 + bg) * 8192;
        float s = 0.f;
#pragma unroll
        for (int j = 0; j < 16; j++) {
            int gc = seg * 16 + j;
            size_t idx = sb + (gc >> 5) * 1024 + ((gc >> 3) & 3) * 256
                       + ((gc >> 2) & 1) * 128 + row * 4 + (gc & 3);
            u32 v = __hip_atomic_load(&hb2[idx], __ATOMIC_RELAXED, __HIP_MEMORY_SCOPE_AGENT);
            s += (bf2f((unsigned short)(v >> 16)) + bf2f((unsigned short)v)) * Wlin[seg * 16 + j];
        }
        hp[row][seg] = s;
    }
    __syncthreads();
    if (tid < 32) {
        float s = 0.f;
#pragma unroll
        for (int j = 0; j < 16; j++) s += hp[tid][j];
        out[bg * 32 + tid] = s + blin[0];
    }
}

extern "C" void kernel_launch(void* const* d_in, const int* in_sizes, int n_in,
                              void* d_out, int out_size, void* d_ws, size_t ws_size,
                              hipStream_t stream) {
    const float* x    = (const float*)d_in[0];
    const float* Wih1 = (const float*)d_in[1];
    const float* Whh1 = (const float*)d_in[2];
    const float* bih1 = (const float*)d_in[3];
    const float* bhh1 = (const float*)d_in[4];
    const float* Wih2 = (const float*)d_in[5];
    const float* Whh2 = (const float*)d_in[6];
    const float* bih2 = (const float*)d_in[7];
    const float* bhh2 = (const float*)d_in[8];
    const float* Wlin = (const float*)d_in[9];
    const float* blin = (const float*)d_in[10];
    float* out = (float*)d_out;

    char* pp = (char*)d_ws;
    unsigned short* w1h = (unsigned short*)pp; pp += (size_t)64 * 9 * 512 * 2;
    unsigned short* w1l = (unsigned short*)pp; pp += (size_t)64 * 9 * 512 * 2;
    unsigned short* w2h = (unsigned short*)pp; pp += (size_t)64 * 16 * 512 * 2;
    unsigned short* w2l = (unsigned short*)pp; pp += (size_t)64 * 16 * 512 * 2;
    float* bias1 = (float*)pp; pp += 1024 * 4;
    float* bias2 = (float*)pp; pp += 1024 * 4;
    char* zero_base = pp;
    u32* hb1 = (u32*)pp; pp += (size_t)2 * 16 * 8192 * 4;   // 1 MB (tiled)
    u32* hb2 = (u32*)pp; pp += (size_t)2 * 16 * 8192 * 4;   // 1 MB (tiled)
    u32* prog = (u32*)pp; pp += 16 * 64 * 4;                 // 64 sub-flags x 16 groups
    size_t zero_bytes = (size_t)(pp - zero_base);

    hipMemsetAsync(zero_base, 0, zero_bytes, stream);
    prep_w<<<64, 256, 0, stream>>>(Wih1, Whh1, bih1, bhh1, Wih2, Whh2, bih2, bhh2,
                                   w1h, w1l, w2h, w2l, bias1, bias2);
    lstm_main<<<256, 512, 0, stream>>>(x, w1h, w1l, w2h, w2l, bias1, bias2,
                                       hb1, hb2, prog, Wlin, blin, out);
}